// Round 9
// baseline (177.940 us; speedup 1.0000x reference)
//
#include <hip/hip_runtime.h>
#include <math.h>

#define NROWS 262144
#define DIM   256
#define NC    64
#define CD    (NC*DIM)       // 16384 floats
#define NBLK  512
#define SEGCAP 8192          // per-class bucket capacity (counts ~4096±200)

// ws float-offset layout:
//  acc     [CD]       @ 0        (atomic, memset 0)
//  svec    [64]       @ 16384    (atomic, memset 0)
//  cursor  [64] int   @ 16448    (atomic, memset 0)
//  bucket  [64*8192] int @ 16512
#define OFF_ACC    0
#define OFF_SVEC   16384
#define OFF_CUR    16448
#define OFF_BUCKET 16512

// DPP 64-lane sum: after these 6 adds, lane 63 holds the full sum.
#define DPP_ADD(v, ctrl) \
    ((v) + __int_as_float(__builtin_amdgcn_update_dpp(0, __float_as_int(v), (ctrl), 0xf, 0xf, true)))

__device__ __forceinline__ float dpp_sum64(float v) {
    v = DPP_ADD(v, 0x111);   // row_shr:1
    v = DPP_ADD(v, 0x112);   // row_shr:2
    v = DPP_ADD(v, 0x114);   // row_shr:4
    v = DPP_ADD(v, 0x118);   // row_shr:8
    v = DPP_ADD(v, 0x142);   // row_bcast:15
    v = DPP_ADD(v, 0x143);   // row_bcast:31
    return v;                // lane 63 = total
}

// ---- k0: one-kernel counting sort into fixed-capacity class segments ----
__global__ __launch_bounds__(512)
void k0_sort(const int* __restrict__ tgt, int* __restrict__ cursor,
             int* __restrict__ bucket)
{
    __shared__ int hist[8][NC];
    __shared__ int offw[8][NC];
    __shared__ int sbase[NC];
    const int tid = threadIdx.x, wid = tid >> 6, lane = tid & 63;
    const int row = blockIdx.x * 512 + wid * 64 + lane;
    const int t = tgt[row];
    const unsigned long long ltm = (lane == 0) ? 0ull : ((~0ull) >> (64 - lane));
    int cnt_v = 0, rank = 0;
    #pragma unroll
    for (int k = 0; k < NC; ++k) {
        unsigned long long m = __ballot(t == k);
        if (lane == k) cnt_v = __popcll(m);
        if (t == k)    rank  = __popcll(m & ltm);
    }
    hist[wid][lane] = cnt_v;
    __syncthreads();
    int off = 0, tot = 0;
    #pragma unroll
    for (int w = 0; w < 8; ++w) {
        int v = hist[w][lane];
        if (w < wid) off += v;
        tot += v;
    }
    offw[wid][lane] = off;
    if (wid == 0) sbase[lane] = atomicAdd(&cursor[lane], tot);
    __syncthreads();
    const int pos = sbase[t] + offw[wid][t] + rank;
    bucket[t * SEGCAP + pos] = row;
}

// ---- k1: streaming gather; wave = 64 entries of ONE class ----
// readlane (scalar) indices, 8-deep rotating pipeline, gated tail.
#define RL(v, j) __builtin_amdgcn_readlane((v), (j))

#define PROC(p, jj)                                                            \
    {                                                                          \
        const float gate = ((jj) < nv) ? ivk : 0.f;                            \
        const float px = (p).x * gate, py = (p).y * gate;                      \
        const float pz = (p).z * gate, pw = (p).w * gate;                      \
        acc.x += px; acc.y += py; acc.z += pz; acc.w += pw;                    \
        const float dx = ck.x - px, dy = ck.y - py;                            \
        const float dz = ck.z - pz, dw = ck.w - pw;                            \
        float ss = dx*dx + dy*dy + dz*dz + dw*dw;                              \
        ss = dpp_sum64(ss);                                                    \
        if (lane == 63 && (jj) < nv) sacc += sqrtf(ss);                        \
    }

__global__ __launch_bounds__(512)
void k1_stream(const float* __restrict__ pred, const float* __restrict__ cent,
               const float* __restrict__ count, const int* __restrict__ cursor,
               const int* __restrict__ bucket, float* __restrict__ ws)
{
    const int tid = threadIdx.x, wid = tid >> 6, lane = tid & 63;
    const int g    = blockIdx.x * 8 + wid;   // 0..4095
    const int c    = g >> 6;                 // class
    const int idx0 = g & 63;                 // slot within class
    const int n    = cursor[c];              // class population (~4096)

    const float4* pred4 = (const float4*)pred;
    const float  ivk = 1.0f / count[c];
    const float4 ck  = ((const float4*)cent)[(size_t)c * 64 + lane];
    float4 acc = make_float4(0.f, 0.f, 0.f, 0.f);
    float  sacc = 0.f;
    bool   any = false;

    for (int s = idx0; s * 64 < n; s += 64) {
        const int e0 = s * 64;
        const int nv = (n - e0 < 64) ? (n - e0) : 64;   // valid entries
        any = true;
        const int ei = e0 + ((lane < nv) ? lane : (nv - 1));
        const int r_lane = bucket[c * SEGCAP + ei];

        int q;
        float4 p0, p1, p2, p3, p4, p5, p6, p7;
        q = RL(r_lane, 0); p0 = pred4[(size_t)q * 64 + lane];
        q = RL(r_lane, 1); p1 = pred4[(size_t)q * 64 + lane];
        q = RL(r_lane, 2); p2 = pred4[(size_t)q * 64 + lane];
        q = RL(r_lane, 3); p3 = pred4[(size_t)q * 64 + lane];
        q = RL(r_lane, 4); p4 = pred4[(size_t)q * 64 + lane];
        q = RL(r_lane, 5); p5 = pred4[(size_t)q * 64 + lane];
        q = RL(r_lane, 6); p6 = pred4[(size_t)q * 64 + lane];
        q = RL(r_lane, 7); p7 = pred4[(size_t)q * 64 + lane];

        #pragma unroll 1
        for (int j = 0; j < 56; j += 8) {
            PROC(p0, j + 0) q = RL(r_lane, j +  8); p0 = pred4[(size_t)q * 64 + lane];
            PROC(p1, j + 1) q = RL(r_lane, j +  9); p1 = pred4[(size_t)q * 64 + lane];
            PROC(p2, j + 2) q = RL(r_lane, j + 10); p2 = pred4[(size_t)q * 64 + lane];
            PROC(p3, j + 3) q = RL(r_lane, j + 11); p3 = pred4[(size_t)q * 64 + lane];
            PROC(p4, j + 4) q = RL(r_lane, j + 12); p4 = pred4[(size_t)q * 64 + lane];
            PROC(p5, j + 5) q = RL(r_lane, j + 13); p5 = pred4[(size_t)q * 64 + lane];
            PROC(p6, j + 6) q = RL(r_lane, j + 14); p6 = pred4[(size_t)q * 64 + lane];
            PROC(p7, j + 7) q = RL(r_lane, j + 15); p7 = pred4[(size_t)q * 64 + lane];
        }
        PROC(p0, 56) PROC(p1, 57) PROC(p2, 58) PROC(p3, 59)
        PROC(p4, 60) PROC(p5, 61) PROC(p6, 62) PROC(p7, 63)
    }

    if (any) {
        const int b = OFF_ACC + c * 256 + lane * 4;
        unsafeAtomicAdd(&ws[b    ], acc.x);
        unsafeAtomicAdd(&ws[b + 1], acc.y);
        unsafeAtomicAdd(&ws[b + 2], acc.z);
        unsafeAtomicAdd(&ws[b + 3], acc.w);
        if (lane == 63) unsafeAtomicAdd(&ws[OFF_SVEC + c], sacc);
    }
}

// ---- k_epi: fused cent_new build + abs-sum + s_final + pairwise + output ----
__global__ __launch_bounds__(1024)
void k_epi(const float* __restrict__ cent, const float* __restrict__ count,
           const float* __restrict__ dist, const float* __restrict__ cw,
           const float* __restrict__ ws, float* __restrict__ out)
{
    __shared__ float cs[CD];          // 64 KB cent_new
    __shared__ float sf_s[NC];
    __shared__ float reda[16];
    __shared__ float redp[16];
    const int tid = threadIdx.x, wid = tid >> 6, lane = tid & 63;

    float a = 0.f;
    #pragma unroll
    for (int k = 0; k < 16; ++k) {
        const int o = k * 1024 + tid;
        const float v = cent[o] + ws[OFF_ACC + o];
        cs[o] = v;
        a += fabsf(v);
    }
    a = dpp_sum64(a);
    if (lane == 63) reda[wid] = a;
    if (tid < NC) sf_s[tid] = sqrtf(dist[tid] + ws[OFF_SVEC + tid]) / count[tid];
    __syncthreads();

    const float4* cs4 = (const float4*)cs;
    float pair = 0.f;                  // valid on lane 63
    #pragma unroll
    for (int ii = 0; ii < 4; ++ii) {
        const int i = wid + ii * 16;
        const float4 ci = cs4[i * 64 + lane];
        const float  si = sf_s[i];
        #pragma unroll 4
        for (int j = 0; j < NC; ++j) {
            if (j == i) continue;
            const float4 cj = cs4[j * 64 + lane];
            const float dx = ci.x - cj.x, dy = ci.y - cj.y;
            const float dz = ci.z - cj.z, dw = ci.w - cj.w;
            float ss = dx*dx + dy*dy + dz*dz + dw*dw;
            ss = dpp_sum64(ss);
            if (lane == 63) pair += cw[i * NC + j] * (si + sf_s[j]) / sqrtf(ss);
        }
    }
    if (lane == 63) redp[wid] = pair;
    __syncthreads();
    if (tid == 0) {
        float ps = 0.f, as = 0.f;
        #pragma unroll
        for (int w = 0; w < 16; ++w) { ps += redp[w]; as += reda[w]; }
        out[0] = ps / 64.0f * 63.0f + as * 1e-6f;
    }
}

extern "C" void kernel_launch(void* const* d_in, const int* in_sizes, int n_in,
                              void* d_out, int out_size, void* d_ws, size_t ws_size,
                              hipStream_t stream)
{
    const float* pred  = (const float*)d_in[0];
    const float* cent  = (const float*)d_in[1];
    const float* dist  = (const float*)d_in[2];
    const float* count = (const float*)d_in[3];
    const float* cw    = (const float*)d_in[4];
    const int*   tgt   = (const int*)d_in[5];
    float* ws  = (float*)d_ws;
    float* out = (float*)d_out;

    int* cur_ptr = (int*)(ws + OFF_CUR);
    int* bkt_ptr = (int*)(ws + OFF_BUCKET);

    // zero atomic regions: acc + svec + cursor
    hipMemsetAsync(d_ws, 0, (size_t)(OFF_CUR + 64) * sizeof(float), stream);

    k0_sort  <<<NBLK, 512, 0, stream>>>(tgt, cur_ptr, bkt_ptr);
    k1_stream<<<NBLK, 512, 0, stream>>>(pred, cent, count, cur_ptr, bkt_ptr, ws);
    k_epi    <<<1,   1024, 0, stream>>>(cent, count, dist, cw, ws, out);
}

// Round 10
// 123.233 us; speedup vs baseline: 1.4439x; 1.4439x over previous
//
#include <hip/hip_runtime.h>
#include <math.h>

#define NROWS 262144
#define DIM   256
#define NC    64
#define CD    (NC*DIM)       // 16384
#define NBLK  512            // k_main blocks, 512 rows each

// ws float-offset layout:
//  acc      [16384]      @ 0
//  svec     [64]         @ 16384
//  cent_new [16384]      @ 16448
//  s_final  [64]         @ 32832
//  abs_part [64]         @ 32896
//  pair_part[64]         @ 32960
//  s_part   [512*64]     @ 33024
//  partials [512*16384]  @ 65792   (~33.8 MB total)
#define OFF_ACC    0
#define OFF_SVEC   16384
#define OFF_CENT   16448
#define OFF_SF     32832
#define OFF_ABS    32896
#define OFF_PAIR   32960
#define OFF_SPART  33024
#define OFF_PART   65792

typedef short  bf16x8 __attribute__((ext_vector_type(8)));
typedef float  f32x16 __attribute__((ext_vector_type(16)));

// DPP 64-lane sum: after these 6 adds, lane 63 holds the full sum.
#define DPP_ADD(v, ctrl) \
    ((v) + __int_as_float(__builtin_amdgcn_update_dpp(0, __float_as_int(v), (ctrl), 0xf, 0xf, true)))

__device__ __forceinline__ float dpp_sum64(float v) {
    v = DPP_ADD(v, 0x111);
    v = DPP_ADD(v, 0x112);
    v = DPP_ADD(v, 0x114);
    v = DPP_ADD(v, 0x118);
    v = DPP_ADD(v, 0x142);
    v = DPP_ADD(v, 0x143);
    return v;                // lane 63 = total
}

// pack two f32 -> two bf16 (RNE) in one u32 (lo = first)
__device__ __forceinline__ unsigned int bf16rne2(float lo, float hi) {
    unsigned int ul = __float_as_uint(lo);
    ul = (ul + 0x7FFFu + ((ul >> 16) & 1u)) >> 16;
    unsigned int uh = __float_as_uint(hi);
    uh = (uh + 0x7FFFu + ((uh >> 16) & 1u)) & 0xFFFF0000u;
    return ul | uh;
}

// ---- k_main: sequential stream; MFMA onehot^T x pred; per-row vec; no atomics ----
__global__ __launch_bounds__(512)
void k_main(const float* __restrict__ pred, const float* __restrict__ cent,
            const float* __restrict__ count, const int* __restrict__ tgt,
            float* __restrict__ ws)
{
    __shared__ unsigned short pbf[64 * 256];   // 32 KB bf16 chunk, row-major [r][d]
    __shared__ int   tgt_s[512];
    __shared__ float inv_s[64];
    __shared__ float vec_s[512];
    __shared__ uint4 afrag[8][64];             // 8 A-frag sets (2 ctiles x 4 ksteps)
    __shared__ float sw_s[8][64];

    const int tid  = threadIdx.x;
    const int w    = tid >> 6;        // 8 waves; wave owns dims [32w, 32w+32)
    const int lane = tid & 63;
    const int base = blockIdx.x * 512;

    tgt_s[tid] = tgt[base + tid];
    if (tid < 64) inv_s[tid] = 1.0f / count[tid];
    __syncthreads();

    const float4* pred4 = (const float4*)pred;
    const float4* cent4 = (const float4*)cent;
    const int d0   = w * 32;
    const int ct_b = w & 1, ks_b = w >> 1;     // this wave's A-build assignment

    f32x16 acc0 = {};   // classes [0,32)  x dims [d0,d0+32)
    f32x16 acc1 = {};   // classes [32,64) x dims [d0,d0+32)

    for (int ch = 0; ch < 8; ++ch) {
        const int rb = ch * 64;

        // ---- A-build: wave w builds set (ct_b, ks_b); k = (lane>>5)*8 + j ----
        {
            const int g8  = (lane >> 5) << 3;
            const int cls = ct_b * 32 + (lane & 31);
            unsigned int u0, u1, u2, u3;
            const int rB = rb + ks_b * 16 + g8;
            int t0 = tgt_s[rB + 0], t1 = tgt_s[rB + 1];
            int t2 = tgt_s[rB + 2], t3 = tgt_s[rB + 3];
            int t4 = tgt_s[rB + 4], t5 = tgt_s[rB + 5];
            int t6 = tgt_s[rB + 6], t7 = tgt_s[rB + 7];
            u0 = ((t0==cls)?0x3F80u:0u) | (((t1==cls)?0x3F80u:0u) << 16);
            u1 = ((t2==cls)?0x3F80u:0u) | (((t3==cls)?0x3F80u:0u) << 16);
            u2 = ((t4==cls)?0x3F80u:0u) | (((t5==cls)?0x3F80u:0u) << 16);
            u3 = ((t6==cls)?0x3F80u:0u) | (((t7==cls)?0x3F80u:0u) << 16);
            afrag[w][lane] = make_uint4(u0, u1, u2, u3);
        }

        // ---- load this wave's 8 rows (row = rb + 8i + w), process ----
        const size_t gr = (size_t)(base + rb) * 64 + lane;
        float4 p0 = pred4[gr + (size_t)(0 + w) * 64];
        float4 p1 = pred4[gr + (size_t)(8 + w) * 64];
        float4 p2 = pred4[gr + (size_t)(16 + w) * 64];
        float4 p3 = pred4[gr + (size_t)(24 + w) * 64];
        float4 p4 = pred4[gr + (size_t)(32 + w) * 64];
        float4 p5 = pred4[gr + (size_t)(40 + w) * 64];
        float4 p6 = pred4[gr + (size_t)(48 + w) * 64];
        float4 p7 = pred4[gr + (size_t)(56 + w) * 64];

        #define ROW(pp, i)                                                     \
        {                                                                      \
            const int rc = 8*(i) + w;                                          \
            const int r  = rb + rc;                                            \
            const int c  = tgt_s[r];                                           \
            const float iv = inv_s[c];                                         \
            const float4 ce = cent4[(size_t)c * 64 + lane];                    \
            const float dx = ce.x - pp.x * iv, dy = ce.y - pp.y * iv;          \
            const float dz = ce.z - pp.z * iv, dw = ce.w - pp.w * iv;          \
            float ss = dx*dx + dy*dy + dz*dz + dw*dw;                          \
            ss = dpp_sum64(ss);                                                \
            if (lane == 63) vec_s[r] = sqrtf(ss);                              \
            *(uint2*)&pbf[rc * 256 + lane * 4] =                               \
                make_uint2(bf16rne2(pp.x, pp.y), bf16rne2(pp.z, pp.w));        \
        }
        ROW(p0, 0) ROW(p1, 1) ROW(p2, 2) ROW(p3, 3)
        ROW(p4, 4) ROW(p5, 5) ROW(p6, 6) ROW(p7, 7)
        #undef ROW
        __syncthreads();

        // ---- MFMA: 4 ksteps x 2 ctiles ----
        #pragma unroll
        for (int ks = 0; ks < 4; ++ks) {
            const int kr  = ks * 16 + ((lane >> 5) << 3);
            const int col = d0 + (lane & 31);
            union { unsigned int u[4]; bf16x8 v; } B;
            #pragma unroll
            for (int p = 0; p < 4; ++p) {
                unsigned int lo = pbf[(kr + 2*p    ) * 256 + col];
                unsigned int hi = pbf[(kr + 2*p + 1) * 256 + col];
                B.u[p] = lo | (hi << 16);
            }
            union { uint4 q; bf16x8 v; } A0, A1;
            A0.q = afrag[ks * 2 + 0][lane];
            A1.q = afrag[ks * 2 + 1][lane];
            acc0 = __builtin_amdgcn_mfma_f32_32x32x16_bf16(A0.v, B.v, acc0, 0, 0, 0);
            acc1 = __builtin_amdgcn_mfma_f32_32x32x16_bf16(A1.v, B.v, acc1, 0, 0, 0);
        }
        __syncthreads();
    }

    // ---- write f32 partials (C/D layout: col=lane&31, row=(reg&3)+8*(reg>>2)+4*(lane>>5)) ----
    float* pp = ws + OFF_PART + (size_t)blockIdx.x * CD;
    const int dim = d0 + (lane & 31);
    #pragma unroll
    for (int reg = 0; reg < 16; ++reg) {
        const int crow = (reg & 3) + 8 * (reg >> 2) + 4 * (lane >> 5);
        pp[(      crow) * 256 + dim] = acc0[reg];
        pp[(32  + crow) * 256 + dim] = acc1[reg];
    }

    // ---- block-end per-class s reduction (no atomics) ----
    {
        const float vv = vec_s[w * 64 + lane];
        const int   cc = tgt_s[w * 64 + lane];
        float accs = 0.f;
        for (int k = 0; k < NC; ++k) {
            float sel = (cc == k) ? vv : 0.f;
            sel = dpp_sum64(sel);
            const float tot = __shfl(sel, 63, 64);
            accs += (lane == k) ? tot : 0.f;
        }
        sw_s[w][lane] = accs;
    }
    __syncthreads();
    if (w == 0) {
        float s = 0.f;
        #pragma unroll
        for (int q = 0; q < 8; ++q) s += sw_s[q][lane];
        ws[OFF_SPART + blockIdx.x * 64 + lane] = s;
    }
}

// ---- k_red: blocks 0..63 reduce acc partials; block 64 reduces s_part ----
__global__ __launch_bounds__(256)
void k_red(float* __restrict__ ws)
{
    const int b = blockIdx.x, t = threadIdx.x;
    if (b < 64) {
        const int e = b * 256 + t;
        const float* pp = ws + OFF_PART + e;
        float s = 0.f;
        #pragma unroll 8
        for (int p = 0; p < NBLK; ++p) s += pp[(size_t)p * CD];
        ws[OFF_ACC + e] = s;
    } else {
        __shared__ float red[4][64];
        const int c = t & 63, g = t >> 6;
        float s = 0.f;
        for (int p = g; p < NBLK; p += 4) s += ws[OFF_SPART + p * 64 + c];
        red[g][c] = s;
        __syncthreads();
        if (t < 64) ws[OFF_SVEC + t] = red[0][t] + red[1][t] + red[2][t] + red[3][t];
    }
}

// ---- k2: cent_new = cent + acc*inv; abs partials; s_final ----
__global__ __launch_bounds__(256)
void k2_build(const float* __restrict__ cent, const float* __restrict__ count,
              const float* __restrict__ dist, float* __restrict__ ws)
{
    const int c = blockIdx.x, i = threadIdx.x;
    const float inv = 1.0f / count[c];
    const int o = c * 256 + i;
    const float val = cent[o] + ws[OFF_ACC + o] * inv;
    ws[OFF_CENT + o] = val;
    float a = fabsf(val);
    #pragma unroll
    for (int off = 32; off > 0; off >>= 1) a += __shfl_xor(a, off, 64);
    __shared__ float ra[4];
    if ((i & 63) == 0) ra[i >> 6] = a;
    __syncthreads();
    if (i == 0) {
        ws[OFF_ABS + c] = ra[0] + ra[1] + ra[2] + ra[3];
        ws[OFF_SF  + c] = sqrtf(dist[c] + ws[OFF_SVEC + c]) / count[c];
    }
}

// ---- k3: pairwise terms (proven R8 version) ----
__global__ __launch_bounds__(256)
void k3_pairs(const float* __restrict__ cw, float* __restrict__ ws)
{
    const int i    = blockIdx.x;
    const int tid  = threadIdx.x;
    const int lane = tid & 63;
    const int w    = tid >> 6;
    const float4* c4 = (const float4*)(ws + OFF_CENT);
    const float*  sf = ws + OFF_SF;

    float4 ci = c4[i * 64 + lane];
    float  si = sf[i];
    float acc = 0.f;
    for (int j = w; j < NC; j += 4) {
        if (j == i) continue;
        float4 cj = c4[j * 64 + lane];
        float dx = ci.x - cj.x, dy = ci.y - cj.y;
        float dz = ci.z - cj.z, dw = ci.w - cj.w;
        float ss = dx*dx + dy*dy + dz*dz + dw*dw;
        #pragma unroll
        for (int o = 32; o > 0; o >>= 1) ss += __shfl_xor(ss, o, 64);
        acc += cw[i * NC + j] * (si + sf[j]) / sqrtf(ss);
    }
    __shared__ float wsum[4];
    if (lane == 0) wsum[w] = acc;
    __syncthreads();
    if (tid == 0) ws[OFF_PAIR + i] = wsum[0] + wsum[1] + wsum[2] + wsum[3];
}

// ---- k4: final scalar ----
__global__ __launch_bounds__(64)
void k4_final(const float* __restrict__ ws, float* __restrict__ out)
{
    const int t = threadIdx.x;
    float a = ws[OFF_ABS + t];
    float p = ws[OFF_PAIR + t];
    #pragma unroll
    for (int o = 32; o > 0; o >>= 1) {
        a += __shfl_xor(a, o, 64);
        p += __shfl_xor(p, o, 64);
    }
    if (t == 0) out[0] = p / 64.0f * 63.0f + a * 1e-6f;
}

extern "C" void kernel_launch(void* const* d_in, const int* in_sizes, int n_in,
                              void* d_out, int out_size, void* d_ws, size_t ws_size,
                              hipStream_t stream)
{
    const float* pred  = (const float*)d_in[0];
    const float* cent  = (const float*)d_in[1];
    const float* dist  = (const float*)d_in[2];
    const float* count = (const float*)d_in[3];
    const float* cw    = (const float*)d_in[4];
    const int*   tgt   = (const int*)d_in[5];
    float* ws  = (float*)d_ws;
    float* out = (float*)d_out;

    // no atomics anywhere -> no memset needed (all read regions fully written first)
    k_main  <<<NBLK, 512, 0, stream>>>(pred, cent, count, tgt, ws);
    k_red   <<<65,   256, 0, stream>>>(ws);
    k2_build<<<NC,   256, 0, stream>>>(cent, count, dist, ws);
    k3_pairs<<<NC,   256, 0, stream>>>(cw, ws);
    k4_final<<<1,     64, 0, stream>>>(ws, out);
}

// Round 11
// 92.822 us; speedup vs baseline: 1.9170x; 1.3276x over previous
//
#include <hip/hip_runtime.h>
#include <math.h>

#define NROWS 262144
#define DIM   256
#define NC    64
#define CD    (NC*DIM)       // 16384
#define NBLK  512            // k_main blocks, 512 rows each

// ws float-offset layout:
//  cent_new [16384]      @ 0
//  s_final  [64]         @ 16384
//  abs_part [64]         @ 16448
//  pair_part[64]         @ 16512
//  s_part   [512*64]     @ 16576
//  s_stage2 [16*64]      @ 49344
//  stage2   [4*16384]    @ 50368
//  partials [512*16384]  @ 115904
#define OFF_CENT   0
#define OFF_SF     16384
#define OFF_ABS    16448
#define OFF_PAIR   16512
#define OFF_SPART  16576
#define OFF_SST2   49344
#define OFF_ST2    50368
#define OFF_PART   115904

typedef short  bf16x8 __attribute__((ext_vector_type(8)));
typedef float  f32x16 __attribute__((ext_vector_type(16)));

// DPP 64-lane sum: after these 6 adds, lane 63 holds the full sum.
#define DPP_ADD(v, ctrl) \
    ((v) + __int_as_float(__builtin_amdgcn_update_dpp(0, __float_as_int(v), (ctrl), 0xf, 0xf, true)))

__device__ __forceinline__ float dpp_sum64(float v) {
    v = DPP_ADD(v, 0x111);
    v = DPP_ADD(v, 0x112);
    v = DPP_ADD(v, 0x114);
    v = DPP_ADD(v, 0x118);
    v = DPP_ADD(v, 0x142);
    v = DPP_ADD(v, 0x143);
    return v;                // lane 63 = total
}

// pack two f32 -> two bf16 (RNE) in one u32 (lo = first)
__device__ __forceinline__ unsigned int bf16rne2(float lo, float hi) {
    unsigned int ul = __float_as_uint(lo);
    ul = (ul + 0x7FFFu + ((ul >> 16) & 1u)) >> 16;
    unsigned int uh = __float_as_uint(hi);
    uh = (uh + 0x7FFFu + ((uh >> 16) & 1u)) & 0xFFFF0000u;
    return ul | uh;
}

// MFMA for one 64-row chunk (4 ksteps x 2 class-tiles); A-frags self-built.
// Identical values to R10's afrag path (content independent of builder wave).
__device__ __forceinline__ void do_mfma_chunk(const unsigned short* pb,
                                              const int* tgts, int rbase,
                                              int lane, int d0,
                                              f32x16& a0r, f32x16& a1r)
{
    const int g8  = (lane >> 5) << 3;
    const int cA  = lane & 31;
    const int cB  = 32 + cA;
    const int col = d0 + cA;
    #pragma unroll
    for (int ks = 0; ks < 4; ++ks) {
        const int rA = rbase + ks * 16 + g8;
        const int t0 = tgts[rA+0], t1 = tgts[rA+1], t2 = tgts[rA+2], t3 = tgts[rA+3];
        const int t4 = tgts[rA+4], t5 = tgts[rA+5], t6 = tgts[rA+6], t7 = tgts[rA+7];
        union { unsigned int u[4]; bf16x8 v; } A0, A1, B;
        A0.u[0] = ((t0==cA)?0x3F80u:0u) | (((t1==cA)?0x3F80u:0u) << 16);
        A0.u[1] = ((t2==cA)?0x3F80u:0u) | (((t3==cA)?0x3F80u:0u) << 16);
        A0.u[2] = ((t4==cA)?0x3F80u:0u) | (((t5==cA)?0x3F80u:0u) << 16);
        A0.u[3] = ((t6==cA)?0x3F80u:0u) | (((t7==cA)?0x3F80u:0u) << 16);
        A1.u[0] = ((t0==cB)?0x3F80u:0u) | (((t1==cB)?0x3F80u:0u) << 16);
        A1.u[1] = ((t2==cB)?0x3F80u:0u) | (((t3==cB)?0x3F80u:0u) << 16);
        A1.u[2] = ((t4==cB)?0x3F80u:0u) | (((t5==cB)?0x3F80u:0u) << 16);
        A1.u[3] = ((t6==cB)?0x3F80u:0u) | (((t7==cB)?0x3F80u:0u) << 16);
        const int kr = ks * 16 + g8;
        #pragma unroll
        for (int p = 0; p < 4; ++p) {
            const unsigned int lo = pb[(kr + 2*p    ) * 256 + col];
            const unsigned int hi = pb[(kr + 2*p + 1) * 256 + col];
            B.u[p] = lo | (hi << 16);
        }
        a0r = __builtin_amdgcn_mfma_f32_32x32x16_bf16(A0.v, B.v, a0r, 0, 0, 0);
        a1r = __builtin_amdgcn_mfma_f32_32x32x16_bf16(A1.v, B.v, a1r, 0, 0, 0);
    }
}

// ---- k_main: streaming MFMA scatter-add; double-buffered; no atomics ----
__global__ __launch_bounds__(512, 4)
void k_main(const float* __restrict__ pred, const float* __restrict__ cent,
            const float* __restrict__ count, const int* __restrict__ tgt,
            float* __restrict__ ws)
{
    __shared__ unsigned short pbf[2][64 * 256];   // 2 x 32 KB bf16 chunk
    __shared__ int   tgt_s[512];
    __shared__ float inv_s[64];
    __shared__ float vec_s[512];
    __shared__ float sw_s[8][64];

    const int tid  = threadIdx.x;
    const int w    = tid >> 6;        // 8 waves; wave owns dims [32w, 32w+32)
    const int lane = tid & 63;
    const int base = blockIdx.x * 512;

    tgt_s[tid] = tgt[base + tid];
    if (tid < 64) inv_s[tid] = 1.0f / count[tid];
    __syncthreads();

    const float4* pred4 = (const float4*)pred;
    const float4* cent4 = (const float4*)cent;
    const int d0 = w * 32;

    f32x16 acc0 = {};   // classes [0,32)  x dims [d0,d0+32)
    f32x16 acc1 = {};   // classes [32,64) x dims [d0,d0+32)

    float4 p0, p1, p2, p3, p4, p5, p6, p7;

#define LOADCH(cc) {                                                           \
    const size_t gr = (size_t)(base + (cc) * 64) * 64 + lane;                  \
    p0 = pred4[gr + (size_t)( 0 + w) * 64];                                    \
    p1 = pred4[gr + (size_t)( 8 + w) * 64];                                    \
    p2 = pred4[gr + (size_t)(16 + w) * 64];                                    \
    p3 = pred4[gr + (size_t)(24 + w) * 64];                                    \
    p4 = pred4[gr + (size_t)(32 + w) * 64];                                    \
    p5 = pred4[gr + (size_t)(40 + w) * 64];                                    \
    p6 = pred4[gr + (size_t)(48 + w) * 64];                                    \
    p7 = pred4[gr + (size_t)(56 + w) * 64]; }

#define ROW(pp, i, cc, b)                                                      \
    {                                                                          \
        const int rc = 8*(i) + w;                                              \
        const int r  = (cc)*64 + rc;                                           \
        const int c  = tgt_s[r];                                               \
        const float iv = inv_s[c];                                             \
        const float4 ce = cent4[(size_t)c * 64 + lane];                        \
        const float dx = ce.x - pp.x * iv, dy = ce.y - pp.y * iv;              \
        const float dz = ce.z - pp.z * iv, dw = ce.w - pp.w * iv;              \
        float ss = dx*dx + dy*dy + dz*dz + dw*dw;                              \
        ss = dpp_sum64(ss);                                                    \
        if (lane == 63) vec_s[r] = sqrtf(ss);                                  \
        *(uint2*)&pbf[b][rc * 256 + lane * 4] =                                \
            make_uint2(bf16rne2(pp.x, pp.y), bf16rne2(pp.z, pp.w));            \
    }

#define ROWS8(cc, b)                                                           \
    ROW(p0, 0, cc, b) ROW(p1, 1, cc, b) ROW(p2, 2, cc, b) ROW(p3, 3, cc, b)    \
    ROW(p4, 4, cc, b) ROW(p5, 5, cc, b) ROW(p6, 6, cc, b) ROW(p7, 7, cc, b)

    // prologue: stage chunk 0 into pbf[0]
    LOADCH(0)
    ROWS8(0, 0)
    __syncthreads();

    #pragma unroll 1
    for (int ch = 0; ch < 7; ++ch) {
        const int cur = ch & 1;
        LOADCH(ch + 1)                                       // issue early (T14)
        do_mfma_chunk(pbf[cur], tgt_s, ch * 64, lane, d0, acc0, acc1);
        ROWS8(ch + 1, cur ^ 1)                               // consume + stage
        __syncthreads();                                     // one barrier/chunk
    }
    do_mfma_chunk(pbf[1], tgt_s, 7 * 64, lane, d0, acc0, acc1);

    // write f32 partials (C/D layout: col=lane&31, row=(reg&3)+8*(reg>>2)+4*(lane>>5))
    float* pp = ws + OFF_PART + (size_t)blockIdx.x * CD;
    const int dim = d0 + (lane & 31);
    #pragma unroll
    for (int reg = 0; reg < 16; ++reg) {
        const int crow = (reg & 3) + 8 * (reg >> 2) + 4 * (lane >> 5);
        pp[(     crow) * 256 + dim] = acc0[reg];
        pp[(32 + crow) * 256 + dim] = acc1[reg];
    }

    // block-end per-class s reduction (no atomics)
    {
        const float vv = vec_s[w * 64 + lane];
        const int   cc = tgt_s[w * 64 + lane];
        float accs = 0.f;
        for (int k = 0; k < NC; ++k) {
            float sel = (cc == k) ? vv : 0.f;
            sel = dpp_sum64(sel);
            const float tot = __shfl(sel, 63, 64);
            accs += (lane == k) ? tot : 0.f;
        }
        sw_s[w][lane] = accs;
    }
    __syncthreads();
    if (w == 0) {
        float s = 0.f;
        #pragma unroll
        for (int q = 0; q < 8; ++q) s += sw_s[q][lane];
        ws[OFF_SPART + blockIdx.x * 64 + lane] = s;
    }
#undef LOADCH
#undef ROW
#undef ROWS8
}

// ---- k_red (WIDE): 1024 blocks reduce partials -> 4 stage2 slabs;
//      16 blocks reduce s_part -> 16 s_stage2 rows ----
__global__ __launch_bounds__(256)
void k_red(float* __restrict__ ws)
{
    const int b = blockIdx.x, t = threadIdx.x;
    __shared__ float red[4][64];
    if (b < 1024) {
        const int pg = b >> 8, eg = b & 255;
        const int e  = eg * 64 + (t & 63);
        const int ps = t >> 6;                     // 0..3
        const float* pp = ws + OFF_PART + e;
        float s = 0.f;
        const int pstart = pg * 128 + ps * 32;
        #pragma unroll 8
        for (int p = pstart; p < pstart + 32; ++p) s += pp[(size_t)p * CD];
        red[ps][t & 63] = s;
        __syncthreads();
        if (t < 64)
            ws[OFF_ST2 + pg * CD + eg * 64 + t]
                = red[0][t] + red[1][t] + red[2][t] + red[3][t];
    } else {
        const int q = b - 1024;                    // 0..15
        const int c = t & 63, pq = t >> 6;
        float s = 0.f;
        #pragma unroll
        for (int i = 0; i < 8; ++i)
            s += ws[OFF_SPART + (q * 32 + pq * 8 + i) * 64 + c];
        red[pq][c] = s;
        __syncthreads();
        if (t < 64)
            ws[OFF_SST2 + q * 64 + t]
                = red[0][t] + red[1][t] + red[2][t] + red[3][t];
    }
}

// ---- k2: cent_new = cent + acc*inv; abs partials; s_final ----
__global__ __launch_bounds__(256)
void k2_build(const float* __restrict__ cent, const float* __restrict__ count,
              const float* __restrict__ dist, float* __restrict__ ws)
{
    const int c = blockIdx.x, i = threadIdx.x;
    const float inv = 1.0f / count[c];
    const int o = c * 256 + i;
    float tsum = 0.f;
    #pragma unroll
    for (int pg = 0; pg < 4; ++pg) tsum += ws[OFF_ST2 + pg * CD + o];
    const float val = cent[o] + tsum * inv;
    ws[OFF_CENT + o] = val;
    float a = fabsf(val);
    #pragma unroll
    for (int off = 32; off > 0; off >>= 1) a += __shfl_xor(a, off, 64);
    __shared__ float ra[4];
    if ((i & 63) == 0) ra[i >> 6] = a;
    __syncthreads();
    if (i == 0) {
        float sv = 0.f;
        #pragma unroll
        for (int q = 0; q < 16; ++q) sv += ws[OFF_SST2 + q * 64 + c];
        ws[OFF_ABS + c] = ra[0] + ra[1] + ra[2] + ra[3];
        ws[OFF_SF  + c] = sqrtf(dist[c] + sv) / count[c];
    }
}

// ---- k3: pairwise terms ----
__global__ __launch_bounds__(256)
void k3_pairs(const float* __restrict__ cw, float* __restrict__ ws)
{
    const int i    = blockIdx.x;
    const int tid  = threadIdx.x;
    const int lane = tid & 63;
    const int w    = tid >> 6;
    const float4* c4 = (const float4*)(ws + OFF_CENT);
    const float*  sf = ws + OFF_SF;

    float4 ci = c4[i * 64 + lane];
    float  si = sf[i];
    float acc = 0.f;
    for (int j = w; j < NC; j += 4) {
        if (j == i) continue;
        float4 cj = c4[j * 64 + lane];
        float dx = ci.x - cj.x, dy = ci.y - cj.y;
        float dz = ci.z - cj.z, dw = ci.w - cj.w;
        float ss = dx*dx + dy*dy + dz*dz + dw*dw;
        #pragma unroll
        for (int o = 32; o > 0; o >>= 1) ss += __shfl_xor(ss, o, 64);
        acc += cw[i * NC + j] * (si + sf[j]) / sqrtf(ss);
    }
    __shared__ float wsum[4];
    if (lane == 0) wsum[w] = acc;
    __syncthreads();
    if (tid == 0) ws[OFF_PAIR + i] = wsum[0] + wsum[1] + wsum[2] + wsum[3];
}

// ---- k4: final scalar ----
__global__ __launch_bounds__(64)
void k4_final(const float* __restrict__ ws, float* __restrict__ out)
{
    const int t = threadIdx.x;
    float a = ws[OFF_ABS + t];
    float p = ws[OFF_PAIR + t];
    #pragma unroll
    for (int o = 32; o > 0; o >>= 1) {
        a += __shfl_xor(a, o, 64);
        p += __shfl_xor(p, o, 64);
    }
    if (t == 0) out[0] = p / 64.0f * 63.0f + a * 1e-6f;
}

extern "C" void kernel_launch(void* const* d_in, const int* in_sizes, int n_in,
                              void* d_out, int out_size, void* d_ws, size_t ws_size,
                              hipStream_t stream)
{
    const float* pred  = (const float*)d_in[0];
    const float* cent  = (const float*)d_in[1];
    const float* dist  = (const float*)d_in[2];
    const float* count = (const float*)d_in[3];
    const float* cw    = (const float*)d_in[4];
    const int*   tgt   = (const int*)d_in[5];
    float* ws  = (float*)d_ws;
    float* out = (float*)d_out;

    // no atomics anywhere -> no memset needed (all read regions fully written first)
    k_main  <<<NBLK, 512, 0, stream>>>(pred, cent, count, tgt, ws);
    k_red   <<<1040, 256, 0, stream>>>(ws);
    k2_build<<<NC,   256, 0, stream>>>(cent, count, dist, ws);
    k3_pairs<<<NC,   256, 0, stream>>>(cw, ws);
    k4_final<<<1,     64, 0, stream>>>(ws, out);
}

// Round 12
// 85.155 us; speedup vs baseline: 2.0896x; 1.0900x over previous
//
#include <hip/hip_runtime.h>
#include <math.h>

#define NROWS 262144
#define DIM   256
#define NC    64
#define CD    (NC*DIM)       // 16384
#define NBLK  512            // k_main blocks, 512 rows each

// ws float-offset layout:
//  cent_new [16384]      @ 0
//  s_final  [64]         @ 16384
//  abs_part [64]         @ 16448
//  pair_part[64]         @ 16512
//  s_part   [512*64]     @ 16576
//  s_stage2 [16*64]      @ 49344
//  stage2   [4*16384]    @ 50368
//  partials [512*16384]  @ 115904
#define OFF_CENT   0
#define OFF_SF     16384
#define OFF_ABS    16448
#define OFF_PAIR   16512
#define OFF_SPART  16576
#define OFF_SST2   49344
#define OFF_ST2    50368
#define OFF_PART   115904

typedef short  bf16x8 __attribute__((ext_vector_type(8)));
typedef float  f32x16 __attribute__((ext_vector_type(16)));

// DPP 64-lane sum: after these 6 adds, lane 63 holds the full sum.
#define DPP_ADD(v, ctrl) \
    ((v) + __int_as_float(__builtin_amdgcn_update_dpp(0, __float_as_int(v), (ctrl), 0xf, 0xf, true)))

__device__ __forceinline__ float dpp_sum64(float v) {
    v = DPP_ADD(v, 0x111);
    v = DPP_ADD(v, 0x112);
    v = DPP_ADD(v, 0x114);
    v = DPP_ADD(v, 0x118);
    v = DPP_ADD(v, 0x142);
    v = DPP_ADD(v, 0x143);
    return v;                // lane 63 = total
}

// pack two f32 -> two bf16 (RNE) in one u32 (lo = first)
__device__ __forceinline__ unsigned int bf16rne2(float lo, float hi) {
    unsigned int ul = __float_as_uint(lo);
    ul = (ul + 0x7FFFu + ((ul >> 16) & 1u)) >> 16;
    unsigned int uh = __float_as_uint(hi);
    uh = (uh + 0x7FFFu + ((uh >> 16) & 1u)) & 0xFFFF0000u;
    return ul | uh;
}
__device__ __forceinline__ float bflo(unsigned int u) { return __uint_as_float(u << 16); }
__device__ __forceinline__ float bfhi(unsigned int u) { return __uint_as_float(u & 0xFFFF0000u); }

// MFMA for one 64-row chunk (4 ksteps x 2 class-tiles); A-frags self-built.
__device__ __forceinline__ void do_mfma_chunk(const unsigned short* pb,
                                              const int* tgts, int rbase,
                                              int lane, int d0,
                                              f32x16& a0r, f32x16& a1r)
{
    const int g8  = (lane >> 5) << 3;
    const int cA  = lane & 31;
    const int cB  = 32 + cA;
    const int col = d0 + cA;
    #pragma unroll
    for (int ks = 0; ks < 4; ++ks) {
        const int rA = rbase + ks * 16 + g8;
        const int t0 = tgts[rA+0], t1 = tgts[rA+1], t2 = tgts[rA+2], t3 = tgts[rA+3];
        const int t4 = tgts[rA+4], t5 = tgts[rA+5], t6 = tgts[rA+6], t7 = tgts[rA+7];
        union { unsigned int u[4]; bf16x8 v; } A0, A1, B;
        A0.u[0] = ((t0==cA)?0x3F80u:0u) | (((t1==cA)?0x3F80u:0u) << 16);
        A0.u[1] = ((t2==cA)?0x3F80u:0u) | (((t3==cA)?0x3F80u:0u) << 16);
        A0.u[2] = ((t4==cA)?0x3F80u:0u) | (((t5==cA)?0x3F80u:0u) << 16);
        A0.u[3] = ((t6==cA)?0x3F80u:0u) | (((t7==cA)?0x3F80u:0u) << 16);
        A1.u[0] = ((t0==cB)?0x3F80u:0u) | (((t1==cB)?0x3F80u:0u) << 16);
        A1.u[1] = ((t2==cB)?0x3F80u:0u) | (((t3==cB)?0x3F80u:0u) << 16);
        A1.u[2] = ((t4==cB)?0x3F80u:0u) | (((t5==cB)?0x3F80u:0u) << 16);
        A1.u[3] = ((t6==cB)?0x3F80u:0u) | (((t7==cB)?0x3F80u:0u) << 16);
        const int kr = ks * 16 + g8;
        #pragma unroll
        for (int p = 0; p < 4; ++p) {
            const unsigned int lo = pb[(kr + 2*p    ) * 256 + col];
            const unsigned int hi = pb[(kr + 2*p + 1) * 256 + col];
            B.u[p] = lo | (hi << 16);
        }
        a0r = __builtin_amdgcn_mfma_f32_32x32x16_bf16(A0.v, B.v, a0r, 0, 0, 0);
        a1r = __builtin_amdgcn_mfma_f32_32x32x16_bf16(A1.v, B.v, a1r, 0, 0, 0);
    }
}

// ---- k_main: streaming MFMA scatter-add; classic 2-barrier; LDS-cached cent ----
__global__ __launch_bounds__(512, 4)
void k_main(const float* __restrict__ pred, const float* __restrict__ cent,
            const float* __restrict__ count, const int* __restrict__ tgt,
            float* __restrict__ ws)
{
    __shared__ unsigned short pbf[64 * 256];   // 32 KB bf16 chunk [r][d]
    __shared__ unsigned short cbf[NC * 256];   // 32 KB bf16 centroids [c][d]
    __shared__ int   tgt_s[512];
    __shared__ float inv_s[64];
    __shared__ float vec_s[512];
    __shared__ float sw_s[8][64];

    const int tid  = threadIdx.x;
    const int w    = tid >> 6;        // 8 waves; wave owns dims [32w, 32w+32)
    const int lane = tid & 63;
    const int base = blockIdx.x * 512;

    tgt_s[tid] = tgt[base + tid];
    if (tid < 64) inv_s[tid] = 1.0f / count[tid];
    {
        const float2* c2 = (const float2*)cent;
        unsigned int* cb32 = (unsigned int*)cbf;
        #pragma unroll
        for (int i = 0; i < 16; ++i) {
            const int o = i * 512 + tid;
            const float2 cf = c2[o];
            cb32[o] = bf16rne2(cf.x, cf.y);
        }
    }
    __syncthreads();

    const float4* pred4 = (const float4*)pred;
    const int d0 = w * 32;

    f32x16 acc0 = {};   // classes [0,32)  x dims [d0,d0+32)
    f32x16 acc1 = {};   // classes [32,64) x dims [d0,d0+32)

    #pragma unroll 1
    for (int ch = 0; ch < 8; ++ch) {
        // stage: load 8 rows (row = ch*64 + 8i + w), all loads issued together
        const size_t gr = (size_t)(base + ch * 64) * 64 + lane;
        float4 p0 = pred4[gr + (size_t)( 0 + w) * 64];
        float4 p1 = pred4[gr + (size_t)( 8 + w) * 64];
        float4 p2 = pred4[gr + (size_t)(16 + w) * 64];
        float4 p3 = pred4[gr + (size_t)(24 + w) * 64];
        float4 p4 = pred4[gr + (size_t)(32 + w) * 64];
        float4 p5 = pred4[gr + (size_t)(40 + w) * 64];
        float4 p6 = pred4[gr + (size_t)(48 + w) * 64];
        float4 p7 = pred4[gr + (size_t)(56 + w) * 64];

#define ROW(pp, i)                                                             \
        {                                                                      \
            const int rc = 8*(i) + w;                                          \
            const int r  = ch * 64 + rc;                                       \
            const int c  = tgt_s[r];                                           \
            const float iv = inv_s[c];                                         \
            const uint2 cu = *(const uint2*)&cbf[c * 256 + lane * 4];          \
            const float dx = bflo(cu.x) - pp.x * iv;                           \
            const float dy = bfhi(cu.x) - pp.y * iv;                           \
            const float dz = bflo(cu.y) - pp.z * iv;                           \
            const float dw = bfhi(cu.y) - pp.w * iv;                           \
            float ss = dx*dx + dy*dy + dz*dz + dw*dw;                          \
            ss = dpp_sum64(ss);                                                \
            if (lane == 63) vec_s[r] = sqrtf(ss);                              \
            *(uint2*)&pbf[rc * 256 + lane * 4] =                               \
                make_uint2(bf16rne2(pp.x, pp.y), bf16rne2(pp.z, pp.w));        \
        }
        ROW(p0, 0) ROW(p1, 1) ROW(p2, 2) ROW(p3, 3)
        ROW(p4, 4) ROW(p5, 5) ROW(p6, 6) ROW(p7, 7)
#undef ROW
        __syncthreads();
        do_mfma_chunk(pbf, tgt_s, ch * 64, lane, d0, acc0, acc1);
        __syncthreads();
    }

    // write f32 partials (C/D layout: col=lane&31, row=(reg&3)+8*(reg>>2)+4*(lane>>5))
    float* pp = ws + OFF_PART + (size_t)blockIdx.x * CD;
    const int dim = d0 + (lane & 31);
    #pragma unroll
    for (int reg = 0; reg < 16; ++reg) {
        const int crow = (reg & 3) + 8 * (reg >> 2) + 4 * (lane >> 5);
        pp[(     crow) * 256 + dim] = acc0[reg];
        pp[(32 + crow) * 256 + dim] = acc1[reg];
    }

    // block-end per-class s reduction (no atomics)
    {
        const float vv = vec_s[w * 64 + lane];
        const int   cc = tgt_s[w * 64 + lane];
        float accs = 0.f;
        for (int k = 0; k < NC; ++k) {
            float sel = (cc == k) ? vv : 0.f;
            sel = dpp_sum64(sel);
            const float tot = __shfl(sel, 63, 64);
            accs += (lane == k) ? tot : 0.f;
        }
        sw_s[w][lane] = accs;
    }
    __syncthreads();
    if (w == 0) {
        float s = 0.f;
        #pragma unroll
        for (int q = 0; q < 8; ++q) s += sw_s[q][lane];
        ws[OFF_SPART + blockIdx.x * 64 + lane] = s;
    }
}

// ---- k_red (WIDE): 1024 blocks reduce partials -> 4 stage2 slabs;
//      16 blocks reduce s_part -> 16 s_stage2 rows ----
__global__ __launch_bounds__(256)
void k_red(float* __restrict__ ws)
{
    const int b = blockIdx.x, t = threadIdx.x;
    __shared__ float red[4][64];
    if (b < 1024) {
        const int pg = b >> 8, eg = b & 255;
        const int e  = eg * 64 + (t & 63);
        const int ps = t >> 6;                     // 0..3
        const float* pp = ws + OFF_PART + e;
        float s = 0.f;
        const int pstart = pg * 128 + ps * 32;
        #pragma unroll 8
        for (int p = pstart; p < pstart + 32; ++p) s += pp[(size_t)p * CD];
        red[ps][t & 63] = s;
        __syncthreads();
        if (t < 64)
            ws[OFF_ST2 + pg * CD + eg * 64 + t]
                = red[0][t] + red[1][t] + red[2][t] + red[3][t];
    } else {
        const int q = b - 1024;                    // 0..15
        const int c = t & 63, pq = t >> 6;
        float s = 0.f;
        #pragma unroll
        for (int i = 0; i < 8; ++i)
            s += ws[OFF_SPART + (q * 32 + pq * 8 + i) * 64 + c];
        red[pq][c] = s;
        __syncthreads();
        if (t < 64)
            ws[OFF_SST2 + q * 64 + t]
                = red[0][t] + red[1][t] + red[2][t] + red[3][t];
    }
}

// ---- k2: cent_new = cent + acc*inv; abs partials; s_final ----
__global__ __launch_bounds__(256)
void k2_build(const float* __restrict__ cent, const float* __restrict__ count,
              const float* __restrict__ dist, float* __restrict__ ws)
{
    const int c = blockIdx.x, i = threadIdx.x;
    const float inv = 1.0f / count[c];
    const int o = c * 256 + i;
    float tsum = 0.f;
    #pragma unroll
    for (int pg = 0; pg < 4; ++pg) tsum += ws[OFF_ST2 + pg * CD + o];
    const float val = cent[o] + tsum * inv;
    ws[OFF_CENT + o] = val;
    float a = fabsf(val);
    #pragma unroll
    for (int off = 32; off > 0; off >>= 1) a += __shfl_xor(a, off, 64);
    __shared__ float ra[4];
    if ((i & 63) == 0) ra[i >> 6] = a;
    __syncthreads();
    if (i == 0) {
        float sv = 0.f;
        #pragma unroll
        for (int q = 0; q < 16; ++q) sv += ws[OFF_SST2 + q * 64 + c];
        ws[OFF_ABS + c] = ra[0] + ra[1] + ra[2] + ra[3];
        ws[OFF_SF  + c] = sqrtf(dist[c] + sv) / count[c];
    }
}

// ---- k3: pairwise terms ----
__global__ __launch_bounds__(256)
void k3_pairs(const float* __restrict__ cw, float* __restrict__ ws)
{
    const int i    = blockIdx.x;
    const int tid  = threadIdx.x;
    const int lane = tid & 63;
    const int w    = tid >> 6;
    const float4* c4 = (const float4*)(ws + OFF_CENT);
    const float*  sf = ws + OFF_SF;

    float4 ci = c4[i * 64 + lane];
    float  si = sf[i];
    float acc = 0.f;
    for (int j = w; j < NC; j += 4) {
        if (j == i) continue;
        float4 cj = c4[j * 64 + lane];
        float dx = ci.x - cj.x, dy = ci.y - cj.y;
        float dz = ci.z - cj.z, dw = ci.w - cj.w;
        float ss = dx*dx + dy*dy + dz*dz + dw*dw;
        #pragma unroll
        for (int o = 32; o > 0; o >>= 1) ss += __shfl_xor(ss, o, 64);
        acc += cw[i * NC + j] * (si + sf[j]) / sqrtf(ss);
    }
    __shared__ float wsum[4];
    if (lane == 0) wsum[w] = acc;
    __syncthreads();
    if (tid == 0) ws[OFF_PAIR + i] = wsum[0] + wsum[1] + wsum[2] + wsum[3];
}

// ---- k4: final scalar ----
__global__ __launch_bounds__(64)
void k4_final(const float* __restrict__ ws, float* __restrict__ out)
{
    const int t = threadIdx.x;
    float a = ws[OFF_ABS + t];
    float p = ws[OFF_PAIR + t];
    #pragma unroll
    for (int o = 32; o > 0; o >>= 1) {
        a += __shfl_xor(a, o, 64);
        p += __shfl_xor(p, o, 64);
    }
    if (t == 0) out[0] = p / 64.0f * 63.0f + a * 1e-6f;
}

extern "C" void kernel_launch(void* const* d_in, const int* in_sizes, int n_in,
                              void* d_out, int out_size, void* d_ws, size_t ws_size,
                              hipStream_t stream)
{
    const float* pred  = (const float*)d_in[0];
    const float* cent  = (const float*)d_in[1];
    const float* dist  = (const float*)d_in[2];
    const float* count = (const float*)d_in[3];
    const float* cw    = (const float*)d_in[4];
    const int*   tgt   = (const int*)d_in[5];
    float* ws  = (float*)d_ws;
    float* out = (float*)d_out;

    // no atomics anywhere -> no memset needed
    k_main  <<<NBLK, 512, 0, stream>>>(pred, cent, count, tgt, ws);
    k_red   <<<1040, 256, 0, stream>>>(ws);
    k2_build<<<NC,   256, 0, stream>>>(cent, count, dist, ws);
    k3_pairs<<<NC,   256, 0, stream>>>(cw, ws);
    k4_final<<<1,     64, 0, stream>>>(ws, out);
}